// Round 5
// baseline (47.943 us; speedup 1.0000x reference)
//
#include <hip/hip_runtime.h>
#include <hip/hip_bf16.h>
#include <cstdint>
#include <cstddef>

#define BB 64
#define SS 2048
#define HH 768
#define LAM 0.0f
#define NEGV -1e30f

// ---------------- Kernel L: recover lengths[b] from token_mask ----------------
// mask[b,s] = (s < len[b]), len in [16, 2047]. One wave per b; two parallel
// probe rounds (64-way then 32-way) instead of 131072 strided line reads.
__global__ void lengths_kernel(const float* __restrict__ token_mask,
                               int* __restrict__ lens) {
    int wv = threadIdx.x >> 6;                 // 16 waves per block
    int b = blockIdx.x * 16 + wv;              // 4 blocks x 16 = 64
    int lane = threadIdx.x & 63;

    // round 1: probe s = lane*32 ; count probes with mask==1 -> ceil(len/32)
    int s1 = lane * 32;
    bool m1 = token_mask[((size_t)b * SS + s1) * HH] > 0.f;
    unsigned long long bal1 = __ballot(m1);
    int cnt1 = (int)__popcll(bal1);            // >=1 since len>=16
    int base = (cnt1 - 1) * 32;                // len in (base, base+32]

    // round 2: probe s = base+1+(lane&31), clamped; count(<len) = len-base-1
    int s2 = base + 1 + (lane & 31);
    if (s2 > SS - 1) s2 = SS - 1;
    bool m2 = token_mask[((size_t)b * SS + s2) * HH] > 0.f;
    unsigned long long bal2 = __ballot(m2) & 0xFFFFFFFFull;  // lanes 0..31
    int cnt2 = (int)__popcll(bal2);
    if (lane == 0) lens[b] = base + 1 + cnt2;
}

// ---------------- Kernel A: scores[b,s] = dot(hidden[b,s,:], w_align[H:2H]) ---
// one wave per (b,s) row; validity from lens (no token_mask traffic at all).
// Invalid rows: no work, no write (B also derives validity from lens).
__global__ void scores_kernel(const float* __restrict__ hidden,
                              const int* __restrict__ lens,
                              const float* __restrict__ w_align,
                              float* __restrict__ scores) {
    int row = blockIdx.x * 4 + (threadIdx.x >> 6);   // 4 waves per block
    int lane = threadIdx.x & 63;
    int b = row >> 11;
    int s = row & (SS - 1);
    if (s >= lens[b]) return;                        // wave-uniform skip
    const float* hrow = hidden + (size_t)row * HH;
    const float* w2 = w_align + HH;
    float acc = 0.f;
#pragma unroll
    for (int r = 0; r < 3; ++r) {
        int idx = r * 256 + lane * 4;
        float4 h = *reinterpret_cast<const float4*>(hrow + idx);
        float4 w = *reinterpret_cast<const float4*>(w2 + idx);
        acc += h.x * w.x + h.y * w.y + h.z * w.z + h.w * w.w;
    }
#pragma unroll
    for (int off = 32; off >= 1; off >>= 1) acc += __shfl_xor(acc, off);
    if (lane == 0) scores[row] = acc;
}

// ---------------- Kernel B: one block per batch row ---------------------------
// 64 blocks x 768 threads (12 waves). Wave 0: Newton tau (z[32]/lane in regs),
// probs write, ballot-compaction of support into LDS. Barrier. All 12 waves
// gather pooled[b,h], thread<->h mapping, 4 support rows in flight.
__global__ __launch_bounds__(768, 1) void tau_pool_kernel(
        const float* __restrict__ hidden,
        const float* __restrict__ pooled_tokens,
        const float* __restrict__ w_align,
        const float* __restrict__ b_align,
        const float* __restrict__ scores,
        const int* __restrict__ lens,
        float* __restrict__ out) {
    __shared__ int   s_idx[SS];
    __shared__ float s_p[SS];
    __shared__ int   s_cnt;

    const int b = blockIdx.x;
    const int t = threadIdx.x;
    const int lane = t & 63;
    const int wv = t >> 6;

    if (wv == 0) {
        const int len = lens[b];

        // --- dotP = dot(pooled_tokens[b], w_align[:H]) + b0 ---
        const float* pt = pooled_tokens + b * HH;
        float dp = 0.f;
#pragma unroll
        for (int i = 0; i < 3; ++i) {
            int idx = i * 256 + lane * 4;
            float4 a = *reinterpret_cast<const float4*>(pt + idx);
            float4 w = *reinterpret_cast<const float4*>(w_align + idx);
            dp += a.x * w.x + a.y * w.y + a.z * w.z + a.w * w.w;
        }
#pragma unroll
        for (int off = 32; off >= 1; off >>= 1) dp += __shfl_xor(dp, off);
        dp += b_align[0];

        // --- load scores: element e = i*256 + lane*4 + c -> z[i*4+c] ---
        const float* sc = scores + b * SS;
        float z[32];
#pragma unroll
        for (int i = 0; i < 8; ++i) {
            int e = i * 256 + lane * 4;
            float4 v = *reinterpret_cast<const float4*>(sc + e);
            z[i * 4 + 0] = (e + 0 < len) ? v.x + dp : NEGV;
            z[i * 4 + 1] = (e + 1 < len) ? v.y + dp : NEGV;
            z[i * 4 + 2] = (e + 2 < len) ? v.z + dp : NEGV;
            z[i * 4 + 3] = (e + 3 < len) ? v.w + dp : NEGV;
        }

        // --- zmax over valid (invalid ~ -1e30 never wins; len>=16) ---
        float mx = z[0];
#pragma unroll
        for (int i = 1; i < 32; ++i) mx = fmaxf(mx, z[i]);
#pragma unroll
        for (int off = 32; off >= 1; off >>= 1) mx = fmaxf(mx, __shfl_xor(mx, off));
#pragma unroll
        for (int i = 0; i < 32; ++i) z[i] -= mx;

        // --- Newton on f(tau) = sum(max(z-tau,0)) - 1 ---
        // tau0=-1: f>=0; monotone increase, active set monotone shrink,
        // exact on stabilization. Count never 0 (max element stays active).
        float tau = -1.0f;
#pragma unroll 1
        for (int it = 0; it < 50; ++it) {
            float a = 0.f, c = 0.f;
#pragma unroll
            for (int i = 0; i < 32; ++i) {
                bool g = z[i] > tau;
                a += g ? z[i] : 0.f;
                c += g ? 1.f : 0.f;
            }
#pragma unroll
            for (int off = 32; off >= 1; off >>= 1) {
                a += __shfl_xor(a, off);
                c += __shfl_xor(c, off);
            }
            float tn = (a - 1.f + LAM) / c;
            if (tn == tau) break;      // wave-uniform
            tau = tn;
        }

        // --- probs: write coalesced float4, compact support into LDS ---
        const float inv = 1.f / (1.f - LAM);
        float p[32];
#pragma unroll
        for (int i = 0; i < 32; ++i) p[i] = fmaxf((z[i] - tau) * inv, 0.f);
        float* po = out + BB * HH + b * SS;
#pragma unroll
        for (int i = 0; i < 8; ++i) {
            float4 v = make_float4(p[i * 4 + 0], p[i * 4 + 1], p[i * 4 + 2], p[i * 4 + 3]);
            *reinterpret_cast<float4*>(po + i * 256 + lane * 4) = v;
        }

        int cnt = 0;
#pragma unroll
        for (int i = 0; i < 8; ++i) {
#pragma unroll
            for (int c = 0; c < 4; ++c) {
                float pv = p[i * 4 + c];
                unsigned long long m = __ballot(pv > 0.f);
                if (pv > 0.f) {
                    int pos = cnt + (int)__popcll(m & ((1ull << lane) - 1ull));
                    s_idx[pos] = i * 256 + lane * 4 + c;
                    s_p[pos] = pv;
                }
                cnt += (int)__popcll(m);
            }
        }
        if (lane == 0) s_cnt = cnt;
    }
    __syncthreads();

    // --- pooled[b,h]: all 12 waves, thread t <-> column h=t, 4 rows in flight -
    const int cnt = s_cnt;
    const float* hb = hidden + (size_t)b * SS * HH;
    float acc = 0.f;
#pragma unroll 1
    for (int j = 0; j < cnt; j += 4) {
        int   i0 = s_idx[j];
        float p0 = s_p[j];
        int   i1 = (j + 1 < cnt) ? s_idx[j + 1] : 0;
        float p1 = (j + 1 < cnt) ? s_p[j + 1] : 0.f;
        int   i2 = (j + 2 < cnt) ? s_idx[j + 2] : 0;
        float p2 = (j + 2 < cnt) ? s_p[j + 2] : 0.f;
        int   i3 = (j + 3 < cnt) ? s_idx[j + 3] : 0;
        float p3 = (j + 3 < cnt) ? s_p[j + 3] : 0.f;
        float h0 = hb[(size_t)i0 * HH + t];
        float h1 = hb[(size_t)i1 * HH + t];
        float h2 = hb[(size_t)i2 * HH + t];
        float h3 = hb[(size_t)i3 * HH + t];
        acc += p0 * h0 + p1 * h1 + p2 * h2 + p3 * h3;
    }
    out[b * HH + t] = acc;
}

// ---------------- fallback kernels (ws too small; mask-based, round-4 path) ---
__global__ void scores_kernel_mask(const float* __restrict__ hidden,
                                   const float* __restrict__ token_mask,
                                   const float* __restrict__ w_align,
                                   float* __restrict__ scores) {
    int row = blockIdx.x * 4 + (threadIdx.x >> 6);
    int lane = threadIdx.x & 63;
    float m = token_mask[(size_t)row * HH];
    if (m == 0.0f) {
        if (lane == 0) scores[row] = NEGV;
        return;
    }
    const float* hrow = hidden + (size_t)row * HH;
    const float* w2 = w_align + HH;
    float acc = 0.f;
#pragma unroll
    for (int r = 0; r < 3; ++r) {
        int idx = r * 256 + lane * 4;
        float4 h = *reinterpret_cast<const float4*>(hrow + idx);
        float4 w = *reinterpret_cast<const float4*>(w2 + idx);
        acc += h.x * w.x + h.y * w.y + h.z * w.z + h.w * w.w;
    }
#pragma unroll
    for (int off = 32; off >= 1; off >>= 1) acc += __shfl_xor(acc, off);
    if (lane == 0) scores[row] = acc;
}

__global__ void sentinel_lens_kernel(const float* __restrict__ scores,
                                     int* __restrict__ lens) {
    // derive lens from sentinel scores for the fallback path: len = count valid
    int b = blockIdx.x;
    int t = threadIdx.x;  // 1024
    int c = 0;
#pragma unroll
    for (int i = 0; i < 2; ++i) {
        float v = scores[b * SS + i * 1024 + t];
        c += (v > -1e29f) ? 1 : 0;
    }
#pragma unroll
    for (int off = 32; off >= 1; off >>= 1) c += __shfl_xor(c, off);
    __shared__ int red[16];
    if ((t & 63) == 0) red[t >> 6] = c;
    __syncthreads();
    if (t == 0) {
        int s = 0;
#pragma unroll
        for (int i = 0; i < 16; ++i) s += red[i];
        lens[b] = s;
    }
}

extern "C" void kernel_launch(void* const* d_in, const int* in_sizes, int n_in,
                              void* d_out, int out_size, void* d_ws, size_t ws_size,
                              hipStream_t stream) {
    const float* hidden        = (const float*)d_in[0];
    const float* token_mask    = (const float*)d_in[1];
    const float* pooled_tokens = (const float*)d_in[2];
    const float* w_align       = (const float*)d_in[3];
    const float* b_align       = (const float*)d_in[4];
    float* out = (float*)d_out;

    const size_t scores_bytes = (size_t)BB * SS * sizeof(float);
    const size_t need = scores_bytes + BB * sizeof(int);

    if (ws_size >= need) {
        float* scores_ws = (float*)d_ws;
        int*   lens      = (int*)((char*)d_ws + scores_bytes);

        lengths_kernel<<<dim3(4), dim3(1024), 0, stream>>>(token_mask, lens);
        scores_kernel<<<dim3((BB * SS) / 4), dim3(256), 0, stream>>>(
            hidden, lens, w_align, scores_ws);
        tau_pool_kernel<<<dim3(BB), dim3(768), 0, stream>>>(
            hidden, pooled_tokens, w_align, b_align, scores_ws, lens, out);
    } else {
        // fallback: scores in the probs region of out (read before overwrite),
        // lens derived from sentinels into the first bytes of ws if available,
        // else reuse out—ws must hold at least 64 ints for this path.
        float* scores_ws = out + BB * HH;
        int* lens = (int*)d_ws;  // 256 bytes
        scores_kernel_mask<<<dim3((BB * SS) / 4), dim3(256), 0, stream>>>(
            hidden, token_mask, w_align, scores_ws);
        sentinel_lens_kernel<<<dim3(BB), dim3(1024), 0, stream>>>(scores_ws, lens);
        tau_pool_kernel<<<dim3(BB), dim3(768), 0, stream>>>(
            hidden, pooled_tokens, w_align, b_align, scores_ws, lens, out);
    }
}